// Round 12
// baseline (999.985 us; speedup 1.0000x reference)
//
#include <hip/hip_runtime.h>
#include <hip/hip_bf16.h>
#include <math.h>

#define N_NODES 50000
#define M_PAD   50048   // 782 * 64
#define N_EDGES 800000
#define N_GRAPHS 100
#define IN_DIM 100
#define D 128
#define N_STEPS 8
#define NBINS (N_NODES * 4)      // (dst, type) bins
#define SCAN_BLOCKS 196          // 196*1024 = 200704 >= NBINS

typedef unsigned short ushort_t;
typedef __bf16 bf16x8 __attribute__((ext_vector_type(8)));
typedef float f32x4 __attribute__((ext_vector_type(4)));

__device__ inline ushort_t f2b(float f) {
  __hip_bfloat16 b = __float2bfloat16(f);
  return *reinterpret_cast<ushort_t*>(&b);
}
__device__ inline float b2f(unsigned int u16) {
  unsigned int x = u16 << 16;
  return __builtin_bit_cast(float, x);
}

// Fused: h[n][d] = padded feature; ah h-part = bf16(h)   (prologue only)
__global__ void pad_cast_kernel(const float* __restrict__ feat, float* __restrict__ h,
                                ushort_t* __restrict__ ah) {
  int idx = blockIdx.x * blockDim.x + threadIdx.x;
  if (idx >= N_NODES * D) return;
  int n = idx >> 7, d = idx & 127;
  float v = (d < IN_DIM) ? feat[n * IN_DIM + d] : 0.0f;
  h[idx] = v;
  ah[(size_t)n * 256 + 128 + d] = f2b(v);
}

// BtS[f][t*128+k] = bf16(W_msg[t][k][f])   (n-major, k-contiguous, K=512)
__global__ void prep_bts(const float* __restrict__ W_msg, ushort_t* __restrict__ BtS) {
  int idx = blockIdx.x * blockDim.x + threadIdx.x;
  if (idx >= 128 * 512) return;
  int f = idx >> 9, kp = idx & 511;
  int t = kp >> 7, k = kp & 127;
  BtS[(size_t)f * 512 + kp] = f2b(W_msg[((size_t)t * 128 + k) * 128 + f]);
}

// Permuted fused GRU weight, n-major k-contiguous bf16.
// col' = g*64 + gate*16 + r ; dim d = g*16 + r ; K: k<128 = a (W_ih), k>=128 = h (W_hh)
__global__ void prep_wg(const float* __restrict__ W_ih, const float* __restrict__ W_hh,
                        const float* __restrict__ b_ih, const float* __restrict__ b_hh,
                        ushort_t* __restrict__ WgT, float* __restrict__ gbias) {
  int idx = blockIdx.x * blockDim.x + threadIdx.x;
  if (idx >= 512 * 256) return;
  int colp = idx >> 8, k = idx & 255;
  int g = colp >> 6, gate = (colp >> 4) & 3, r = colp & 15;
  int d = g * 16 + r;
  float v;
  if (gate == 3)      v = (k < 128) ? 0.f : W_hh[(size_t)(256 + d) * 128 + (k - 128)];
  else if (gate == 2) v = (k < 128) ? W_ih[(size_t)(256 + d) * 128 + k] : 0.f;
  else {
    int j0 = (gate == 0) ? d : 128 + d;
    v = (k < 128) ? W_ih[(size_t)j0 * 128 + k] : W_hh[(size_t)j0 * 128 + (k - 128)];
  }
  WgT[(size_t)colp * 256 + k] = f2b(v);
  if (k == 0) {
    float bb = (gate == 0) ? b_ih[d] + b_hh[d]
             : (gate == 1) ? b_ih[128 + d] + b_hh[128 + d]
             : (gate == 2) ? b_ih[256 + d] : b_hh[256 + d];
    gbias[colp] = bb;
  }
}

// ---- type-segmented CSR build over NBINS = dst*4+type ----
__global__ void hist_kernel(const int* __restrict__ edst, const int* __restrict__ etype,
                            int* __restrict__ cnt2, int* __restrict__ rank) {
  int e = blockIdx.x * 256 + threadIdx.x;
  if (e >= N_EDGES) return;
  rank[e] = atomicAdd(&cnt2[edst[e] * 4 + etype[e]], 1);
}

// 3-phase scan: A) per-block inclusive scan + block sums
__global__ __launch_bounds__(1024) void scanA(const int* __restrict__ cnt2,
                                              int* __restrict__ tmp, int* __restrict__ bsum) {
  __shared__ int wsum[16];
  int b = blockIdx.x, t = threadIdx.x;
  int i = b * 1024 + t;
  int lane = t & 63, wid = t >> 6;
  int x = (i < NBINS) ? cnt2[i] : 0;
  #pragma unroll
  for (int s = 1; s < 64; s <<= 1) {
    int y = __shfl_up(x, s, 64);
    if (lane >= s) x += y;
  }
  if (lane == 63) wsum[wid] = x;
  __syncthreads();
  if (wid == 0) {
    int w = (lane < 16) ? wsum[lane] : 0;
    #pragma unroll
    for (int s = 1; s < 16; s <<= 1) {
      int y = __shfl_up(w, s, 64);
      if (lane >= s) w += y;
    }
    if (lane < 16) wsum[lane] = w;
  }
  __syncthreads();
  int wb = (wid > 0) ? wsum[wid - 1] : 0;
  tmp[i] = wb + x;
  if (t == 1023) bsum[b] = wsum[15];
}

// B) one wave scans the SCAN_BLOCKS block sums -> exclusive prefixes
__global__ __launch_bounds__(64) void scanB(const int* __restrict__ bsum,
                                            int* __restrict__ bpre) {
  int lane = threadIdx.x;
  int carry = 0;
  for (int base = 0; base < SCAN_BLOCKS; base += 64) {
    int idx = base + lane;
    int v = (idx < SCAN_BLOCKS) ? bsum[idx] : 0;
    int x = v;
    #pragma unroll
    for (int s = 1; s < 64; s <<= 1) {
      int y = __shfl_up(x, s, 64);
      if (lane >= s) x += y;
    }
    if (idx < SCAN_BLOCKS) bpre[idx] = carry + x - v;
    carry += __shfl(x, 63, 64);
  }
}

// C) offs2[i+1] = tmp[i] + bpre[block]
__global__ __launch_bounds__(1024) void scanC(const int* __restrict__ tmp,
                                              const int* __restrict__ bpre,
                                              int* __restrict__ offs2) {
  int b = blockIdx.x, t = threadIdx.x;
  int i = b * 1024 + t;
  if (i < NBINS) offs2[i + 1] = tmp[i] + bpre[b];
  if (i == 0) offs2[0] = 0;
}

__global__ void fill_kernel(const int* __restrict__ esrc, const int* __restrict__ edst,
                            const int* __restrict__ etype, const int* __restrict__ offs2,
                            const int* __restrict__ rank, int* __restrict__ payload) {
  int e = blockIdx.x * 256 + threadIdx.x;
  if (e >= N_EDGES) return;
  int key = edst[e] * 4 + etype[e];
  payload[offs2[key] + rank[e]] = esrc[e];
}

// ROUND-6 gather, verbatim (best measured). One wave per node; payload
// prefetched one dword/lane; src broadcast via __shfl; per-type segments
// with 4-wide unroll. r7/r8/r9 scalarization attempts all regressed
// (89-106 us, VALUBusy 59-90%). Do not retry.
__global__ __launch_bounds__(256) void gather_kernel(const int* __restrict__ offs2,
    const int* __restrict__ payload, const ushort_t* __restrict__ hb,
    ushort_t* __restrict__ S, float* __restrict__ cntf) {
  int n = blockIdx.x * 4 + (threadIdx.x >> 6);
  int lane = threadIdx.x & 63;
  if (n >= N_NODES) return;
  int bb[5];
  #pragma unroll
  for (int k = 0; k < 5; ++k) bb[k] = offs2[n * 4 + k];
  float a[4][2] = {{0.f, 0.f}, {0.f, 0.f}, {0.f, 0.f}, {0.f, 0.f}};
  const ushort_t* hrow = hb + 128 + lane * 2;
  for (int base = bb[0]; base < bb[4]; base += 64) {
    int lim = min(bb[4], base + 64);
    int cnt = lim - base;
    int pe = (lane < cnt) ? payload[base + lane] : 0;
    #pragma unroll
    for (int t = 0; t < 4; ++t) {
      int lo = max(bb[t], base), hi = min(bb[t + 1], lim);
      int i = lo;
      for (; i + 4 <= hi; i += 4) {
        int s0 = __shfl(pe, i - base, 64);
        int s1 = __shfl(pe, i + 1 - base, 64);
        int s2 = __shfl(pe, i + 2 - base, 64);
        int s3 = __shfl(pe, i + 3 - base, 64);
        unsigned int u0 = *(const unsigned int*)(hrow + (size_t)s0 * 256);
        unsigned int u1 = *(const unsigned int*)(hrow + (size_t)s1 * 256);
        unsigned int u2 = *(const unsigned int*)(hrow + (size_t)s2 * 256);
        unsigned int u3 = *(const unsigned int*)(hrow + (size_t)s3 * 256);
        a[t][0] += b2f(u0 & 0xffff) + b2f(u1 & 0xffff) + b2f(u2 & 0xffff) + b2f(u3 & 0xffff);
        a[t][1] += b2f(u0 >> 16) + b2f(u1 >> 16) + b2f(u2 >> 16) + b2f(u3 >> 16);
      }
      for (; i < hi; ++i) {
        int s0 = __shfl(pe, i - base, 64);
        unsigned int u0 = *(const unsigned int*)(hrow + (size_t)s0 * 256);
        a[t][0] += b2f(u0 & 0xffff);
        a[t][1] += b2f(u0 >> 16);
      }
    }
  }
  #pragma unroll
  for (int t = 0; t < 4; ++t) {
    unsigned int packed = (unsigned int)f2b(a[t][0]) | ((unsigned int)f2b(a[t][1]) << 16);
    *(unsigned int*)(S + (size_t)n * 512 + t * 128 + lane * 2) = packed;
    if (lane == 0) cntf[n * 4 + t] = (float)(bb[t + 1] - bb[t]);
  }
}

// ---- bf16 MFMA GEMM, 64(M)x128(N) tile, 4 waves (each 32x64), 16x16x32 ----
// Epilogues stage results through the freed As/Bs LDS region and emit
// full-line coalesced stores. Round-11 counters: direct strided stores gave
// WRITE_SIZE 37.5 MB vs 12.8 ideal (partial-128B-line RMW) + ~12 MB
// write-allocate FETCH inflation.
// MODE 2: a-GEMM (K=512, N=128): val = acc + sum_t cnt[m][t]*b_msg[t][n]; bf16 -> ah a-part.
// MODE 1: GRU epilogue (permuted gate cols); h fp32 in place; bf16 h -> ah_next h-part.
template <int MODE>
__global__ __launch_bounds__(256) void mfma_gemm(
    const ushort_t* __restrict__ A, int lda, int K,
    const ushort_t* __restrict__ Bt,
    const float* __restrict__ bias, const float* __restrict__ b_msg,
    const float* __restrict__ cntf,
    ushort_t* __restrict__ ah_out, float* __restrict__ h) {
  __shared__ __align__(16) unsigned char smem[15360];
  ushort_t* As = (ushort_t*)smem;           // [64][40]  (80B row stride)
  ushort_t* Bs = (ushort_t*)(smem + 5120);  // [128][40]
  const int m0 = blockIdx.x * 64, n0 = blockIdx.y * 128;
  int tid = threadIdx.x;
  int wave = tid >> 6, lane = tid & 63;
  int wm = (wave & 1) * 32, wn = (wave >> 1) * 64;
  int quad = lane >> 4, l16 = lane & 15;
  f32x4 acc[2][4];
  #pragma unroll
  for (int i = 0; i < 2; ++i)
    #pragma unroll
    for (int j = 0; j < 4; ++j) acc[i][j] = (f32x4){0.f, 0.f, 0.f, 0.f};

  for (int k0 = 0; k0 < K; k0 += 32) {
    {
      int r = tid >> 2;
      int kc = (tid & 3) * 8;
      *(uint4*)&As[r * 40 + kc] = *(const uint4*)(A + (size_t)(m0 + r) * lda + k0 + kc);
      #pragma unroll
      for (int i = 0; i < 2; ++i) {
        int rb = r + i * 64;
        *(uint4*)&Bs[rb * 40 + kc] = *(const uint4*)(Bt + (size_t)(n0 + rb) * K + k0 + kc);
      }
    }
    __syncthreads();
    bf16x8 af[2], bfr[4];
    #pragma unroll
    for (int i = 0; i < 2; ++i) af[i] = *(const bf16x8*)&As[(wm + i * 16 + l16) * 40 + quad * 8];
    #pragma unroll
    for (int j = 0; j < 4; ++j) bfr[j] = *(const bf16x8*)&Bs[(wn + j * 16 + l16) * 40 + quad * 8];
    #pragma unroll
    for (int i = 0; i < 2; ++i)
      #pragma unroll
      for (int j = 0; j < 4; ++j)
        acc[i][j] = __builtin_amdgcn_mfma_f32_16x16x32_bf16(af[i], bfr[j], acc[i][j], 0, 0, 0);
    __syncthreads();
  }
  // k-loop ends with a barrier: LDS is free for epilogue staging.

  if (MODE == 2) {
    // n0 == 0 (N=128). Two 32-row passes through LDS (stride 136 ushorts =
    // 272B: 16B-aligned, odd bank step). Final stores: 256B/row contiguous.
    ushort_t* Ep = (ushort_t*)smem;
    float bm[4][4];  // [j][t]
    #pragma unroll
    for (int j = 0; j < 4; ++j)
      #pragma unroll
      for (int t = 0; t < 4; ++t)
        bm[j][t] = b_msg[t * 128 + wn + j * 16 + l16];
    #pragma unroll
    for (int p = 0; p < 2; ++p) {
      if (p) __syncthreads();
      #pragma unroll
      for (int reg = 0; reg < 4; ++reg) {
        int slot = (wm >> 5) * 16 + quad * 4 + reg;
        int m = m0 + wm + p * 16 + quad * 4 + reg;
        float4 c = *(const float4*)(cntf + (size_t)m * 4);
        #pragma unroll
        for (int j = 0; j < 4; ++j) {
          float val = acc[p][j][reg] + c.x * bm[j][0] + c.y * bm[j][1]
                                     + c.z * bm[j][2] + c.w * bm[j][3];
          Ep[slot * 136 + wn + j * 16 + l16] = f2b(val);
        }
      }
      __syncthreads();
      #pragma unroll
      for (int c2 = 0; c2 < 2; ++c2) {
        int chunk = tid + 256 * c2;            // 512 x 16B chunks = 32 rows x 256B
        int slot = chunk >> 4, sub = chunk & 15;
        int m = m0 + (slot & 15) + (slot >> 4) * 32 + p * 16;
        *(uint4*)(ah_out + (size_t)m * 256 + sub * 8) =
            *(const uint4*)&Ep[slot * 136 + sub * 8];
      }
    }
  } else {
    // Block covers dims [db, db+32) x 64 rows. Stage h fp32 (stride 36 f32 =
    // 144B) + ah bf16 (stride 40 us = 80B), then full-line stores.
    float* Hp = (float*)smem;                       // 64 x 36 f32 = 9216B
    ushort_t* Ap = (ushort_t*)(smem + 9216);        // 64 x 40 us = 5120B
    int db = (n0 >> 6) * 16;
    int dim_loc = (wn >> 6) * 16 + l16;
    float br = bias[n0 + wn + l16];
    float bz = bias[n0 + wn + 16 + l16];
    float bi = bias[n0 + wn + 32 + l16];
    float bh = bias[n0 + wn + 48 + l16];
    #pragma unroll
    for (int i = 0; i < 2; ++i)
      #pragma unroll
      for (int reg = 0; reg < 4; ++reg) {
        int r_loc = wm + i * 16 + quad * 4 + reg;
        int m = m0 + r_loc;
        float pr  = acc[i][0][reg] + br;
        float pz  = acc[i][1][reg] + bz;
        float in_ = acc[i][2][reg] + bi;
        float hn  = acc[i][3][reg] + bh;
        float r = 1.0f / (1.0f + expf(-pr));
        float z = 1.0f / (1.0f + expf(-pz));
        float nn = tanhf(in_ + r * hn);
        size_t hi = (size_t)m * 128 + db + dim_loc;
        float hv = (1.0f - z) * nn + z * h[hi];
        Hp[r_loc * 36 + dim_loc] = hv;
        Ap[r_loc * 40 + dim_loc] = f2b(hv);
      }
    __syncthreads();
    #pragma unroll
    for (int c2 = 0; c2 < 2; ++c2) {
      int chunk = tid + 256 * c2;              // 512 x 16B = 64 rows x 128B (h)
      int row = chunk >> 3, sub = chunk & 7;
      *(uint4*)(h + (size_t)(m0 + row) * 128 + db + sub * 4) =
          *(const uint4*)&Hp[row * 36 + sub * 4];
    }
    {
      int row = tid >> 2, sub = tid & 3;       // 256 x 16B = 64 rows x 64B (ah)
      *(uint4*)(ah_out + (size_t)(m0 + row) * 256 + 128 + db + sub * 8) =
          *(const uint4*)&Ap[row * 40 + sub * 8];
    }
  }
}

// partial pooling: grid (graph, chunk); 8-way atomic contention max.
__global__ __launch_bounds__(128) void pool_kernel(const float* __restrict__ h,
    const int* __restrict__ gids, float* __restrict__ pooled, float* __restrict__ gcnt) {
  __shared__ int lo_s, hi_s;
  int g = blockIdx.x, c = blockIdx.y, d = threadIdx.x;
  if (d == 0) {
    int lo = 0, hi = N_NODES;
    while (lo < hi) { int mid = (lo + hi) >> 1; if (gids[mid] < g) lo = mid + 1; else hi = mid; }
    lo_s = lo;
    int lo2 = lo, hi2 = N_NODES;
    while (lo2 < hi2) { int mid = (lo2 + hi2) >> 1; if (gids[mid] < g + 1) lo2 = mid + 1; else hi2 = mid; }
    hi_s = lo2;
  }
  __syncthreads();
  int lo = lo_s, hi = hi_s;
  int len = hi - lo;
  int b = lo + (int)(((long long)len * c) >> 3);
  int e = lo + (int)(((long long)len * (c + 1)) >> 3);
  float s = 0.f;
  for (int n = b; n < e; ++n) s += h[(size_t)n * 128 + d];
  if (e > b) atomicAdd(&pooled[g * 128 + d], s);
  if (c == 0 && d == 0) gcnt[g] = (float)len;
}

__global__ __launch_bounds__(256) void classifier_kernel(
    const float* __restrict__ pooled, const float* __restrict__ gcnt,
    const float* __restrict__ W1, const float* __restrict__ b1,
    const float* __restrict__ W2, const float* __restrict__ b2,
    float* __restrict__ out) {
  __shared__ float p[D];
  __shared__ float hid[256];
  __shared__ float wsum[4];
  int g = blockIdx.x;
  int t = threadIdx.x;
  float cnt = fmaxf(gcnt[g], 1.0f);
  if (t < D) p[t] = pooled[g * D + t] / cnt;
  __syncthreads();
  float acc = b1[t];
  const float* w = W1 + (size_t)t * D;
  for (int k = 0; k < D; ++k) acc += p[k] * w[k];
  hid[t] = fmaxf(acc, 0.0f);
  __syncthreads();
  float v = hid[t] * W2[t];
  for (int off = 32; off > 0; off >>= 1) v += __shfl_down(v, off, 64);
  if ((t & 63) == 0) wsum[t >> 6] = v;
  __syncthreads();
  if (t == 0) {
    float s = wsum[0] + wsum[1] + wsum[2] + wsum[3] + b2[0];
    out[g] = 1.0f / (1.0f + expf(-s));
  }
}

extern "C" void kernel_launch(void* const* d_in, const int* in_sizes, int n_in,
                              void* d_out, int out_size, void* d_ws, size_t ws_size,
                              hipStream_t stream) {
  const float* features = (const float*)d_in[0];
  const int* esrc  = (const int*)d_in[1];
  const int* edst  = (const int*)d_in[2];
  const int* etype = (const int*)d_in[3];
  const int* gids  = (const int*)d_in[4];
  const float* W_msg = (const float*)d_in[5];
  const float* b_msg = (const float*)d_in[6];
  const float* W_ih  = (const float*)d_in[7];
  const float* W_hh  = (const float*)d_in[8];
  const float* b_ih  = (const float*)d_in[9];
  const float* b_hh  = (const float*)d_in[10];
  const float* W1 = (const float*)d_in[11];
  const float* b1 = (const float*)d_in[12];
  const float* W2 = (const float*)d_in[13];
  const float* b2 = (const float*)d_in[14];
  float* out = (float*)d_out;

  char* ws = (char*)d_ws;
  size_t off_b = 0;
  auto alloc = [&](size_t bytes) -> void* {
    void* p = ws + off_b;
    off_b += (bytes + 255) & ~(size_t)255;
    return p;
  };
  float*    h      = (float*)alloc((size_t)M_PAD * 128 * 4);      // 25.6 MB fp32 master
  ushort_t* ahA    = (ushort_t*)alloc((size_t)M_PAD * 256 * 2);   // [a|h] bf16
  ushort_t* ahB    = (ushort_t*)alloc((size_t)M_PAD * 256 * 2);   // ping-pong partner
  ushort_t* S      = (ushort_t*)alloc((size_t)M_PAD * 512 * 2);   // 51.2 MB bf16
  float*    cntf   = (float*)alloc((size_t)M_PAD * 4 * 4);        // per-node type counts
  ushort_t* BtS    = (ushort_t*)alloc(128 * 512 * 2);
  ushort_t* WgT    = (ushort_t*)alloc(512 * 256 * 2);
  float*    gbias  = (float*)alloc(512 * 4);
  int*      cnt2   = (int*)alloc((size_t)NBINS * 4);
  int*      offs2  = (int*)alloc((size_t)(NBINS + 1) * 4);
  int*      rank   = (int*)alloc((size_t)N_EDGES * 4);
  int*      tmp    = (int*)alloc((size_t)SCAN_BLOCKS * 1024 * 4);
  int*      bsum   = (int*)alloc(SCAN_BLOCKS * 4);
  int*      bpre   = (int*)alloc(SCAN_BLOCKS * 4);
  int*      payload= (int*)alloc((size_t)N_EDGES * 4);
  float*    pooled = (float*)alloc(N_GRAPHS * 128 * 4);
  float*    gcnt   = (float*)alloc(N_GRAPHS * 4);

  // ---- prologue ----
  pad_cast_kernel<<<(N_NODES * 128 + 255) / 256, 256, 0, stream>>>(features, h, ahA);
  prep_bts<<<(128 * 512 + 255) / 256, 256, 0, stream>>>(W_msg, BtS);
  prep_wg<<<(512 * 256 + 255) / 256, 256, 0, stream>>>(W_ih, W_hh, b_ih, b_hh, WgT, gbias);
  hipMemsetAsync(cnt2, 0, (size_t)NBINS * 4, stream);
  hist_kernel<<<(N_EDGES + 255) / 256, 256, 0, stream>>>(edst, etype, cnt2, rank);
  scanA<<<SCAN_BLOCKS, 1024, 0, stream>>>(cnt2, tmp, bsum);
  scanB<<<1, 64, 0, stream>>>(bsum, bpre);
  scanC<<<SCAN_BLOCKS, 1024, 0, stream>>>(tmp, bpre, offs2);
  fill_kernel<<<(N_EDGES + 255) / 256, 256, 0, stream>>>(esrc, edst, etype, offs2, rank, payload);

  ushort_t* cur = ahA;
  ushort_t* nxt = ahB;
  for (int step = 0; step < N_STEPS; ++step) {
    // S[n][t][:] = sum of h_src (bf16) over type-t in-edges
    gather_kernel<<<(N_NODES + 3) / 4, 256, 0, stream>>>(offs2, payload, cur, S, cntf);
    // a-part of cur = bf16(S @ [W_0;..;W_3] + cnt-weighted b_msg)
    mfma_gemm<2><<<dim3(M_PAD / 64, 1), 256, 0, stream>>>(
        S, 512, 512, BtS, nullptr, b_msg, cntf, cur, nullptr);
    // fused GRU GEMM + gate epilogue: fp32 h in place, bf16 h into nxt
    mfma_gemm<1><<<dim3(M_PAD / 64, 4), 256, 0, stream>>>(
        cur, 256, 256, WgT, gbias, nullptr, nullptr, nxt, h);
    ushort_t* t2 = cur; cur = nxt; nxt = t2;
  }

  hipMemsetAsync(pooled, 0, (size_t)N_GRAPHS * 128 * 4, stream);
  pool_kernel<<<dim3(N_GRAPHS, 8), 128, 0, stream>>>(h, gids, pooled, gcnt);
  classifier_kernel<<<N_GRAPHS, 256, 0, stream>>>(pooled, gcnt, W1, b1, W2, b2, out);
}

// Round 13
// 989.119 us; speedup vs baseline: 1.0110x; 1.0110x over previous
//
#include <hip/hip_runtime.h>
#include <hip/hip_bf16.h>
#include <math.h>

#define N_NODES 50000
#define M_PAD   50048   // 782 * 64
#define N_EDGES 800000
#define N_GRAPHS 100
#define IN_DIM 100
#define D 128
#define N_STEPS 8
#define NBINS (N_NODES * 4)      // (dst, type) bins
#define SCAN_BLOCKS 196          // 196*1024 = 200704 >= NBINS

typedef unsigned short ushort_t;
typedef __bf16 bf16x8 __attribute__((ext_vector_type(8)));
typedef float f32x4 __attribute__((ext_vector_type(4)));

__device__ inline ushort_t f2b(float f) {
  __hip_bfloat16 b = __float2bfloat16(f);
  return *reinterpret_cast<ushort_t*>(&b);
}
__device__ inline float b2f(unsigned int u16) {
  unsigned int x = u16 << 16;
  return __builtin_bit_cast(float, x);
}

// async global->LDS, 16B per lane; lds dest = wave-uniform base + lane*16.
__device__ __attribute__((always_inline)) inline void gld16(const ushort_t* g, ushort_t* l) {
  __builtin_amdgcn_global_load_lds(
      (const __attribute__((address_space(1))) void*)g,
      (__attribute__((address_space(3))) void*)l, 16, 0, 0);
}

// Fused: h[n][d] = padded feature; ah h-part = bf16(h)   (prologue only)
__global__ void pad_cast_kernel(const float* __restrict__ feat, float* __restrict__ h,
                                ushort_t* __restrict__ ah) {
  int idx = blockIdx.x * blockDim.x + threadIdx.x;
  if (idx >= N_NODES * D) return;
  int n = idx >> 7, d = idx & 127;
  float v = (d < IN_DIM) ? feat[n * IN_DIM + d] : 0.0f;
  h[idx] = v;
  ah[(size_t)n * 256 + 128 + d] = f2b(v);
}

// BtS[f][t*128+k] = bf16(W_msg[t][k][f])   (n-major, k-contiguous, K=512)
__global__ void prep_bts(const float* __restrict__ W_msg, ushort_t* __restrict__ BtS) {
  int idx = blockIdx.x * blockDim.x + threadIdx.x;
  if (idx >= 128 * 512) return;
  int f = idx >> 9, kp = idx & 511;
  int t = kp >> 7, k = kp & 127;
  BtS[(size_t)f * 512 + kp] = f2b(W_msg[((size_t)t * 128 + k) * 128 + f]);
}

// Permuted fused GRU weight, n-major k-contiguous bf16.
// col' = g*64 + gate*16 + r ; dim d = g*16 + r ; K: k<128 = a (W_ih), k>=128 = h (W_hh)
__global__ void prep_wg(const float* __restrict__ W_ih, const float* __restrict__ W_hh,
                        const float* __restrict__ b_ih, const float* __restrict__ b_hh,
                        ushort_t* __restrict__ WgT, float* __restrict__ gbias) {
  int idx = blockIdx.x * blockDim.x + threadIdx.x;
  if (idx >= 512 * 256) return;
  int colp = idx >> 8, k = idx & 255;
  int g = colp >> 6, gate = (colp >> 4) & 3, r = colp & 15;
  int d = g * 16 + r;
  float v;
  if (gate == 3)      v = (k < 128) ? 0.f : W_hh[(size_t)(256 + d) * 128 + (k - 128)];
  else if (gate == 2) v = (k < 128) ? W_ih[(size_t)(256 + d) * 128 + k] : 0.f;
  else {
    int j0 = (gate == 0) ? d : 128 + d;
    v = (k < 128) ? W_ih[(size_t)j0 * 128 + k] : W_hh[(size_t)j0 * 128 + (k - 128)];
  }
  WgT[(size_t)colp * 256 + k] = f2b(v);
  if (k == 0) {
    float bb = (gate == 0) ? b_ih[d] + b_hh[d]
             : (gate == 1) ? b_ih[128 + d] + b_hh[128 + d]
             : (gate == 2) ? b_ih[256 + d] : b_hh[256 + d];
    gbias[colp] = bb;
  }
}

// ---- type-segmented CSR build over NBINS = dst*4+type ----
__global__ void hist_kernel(const int* __restrict__ edst, const int* __restrict__ etype,
                            int* __restrict__ cnt2, int* __restrict__ rank) {
  int e = blockIdx.x * 256 + threadIdx.x;
  if (e >= N_EDGES) return;
  rank[e] = atomicAdd(&cnt2[edst[e] * 4 + etype[e]], 1);
}

// 3-phase scan: A) per-block inclusive scan + block sums
__global__ __launch_bounds__(1024) void scanA(const int* __restrict__ cnt2,
                                              int* __restrict__ tmp, int* __restrict__ bsum) {
  __shared__ int wsum[16];
  int b = blockIdx.x, t = threadIdx.x;
  int i = b * 1024 + t;
  int lane = t & 63, wid = t >> 6;
  int x = (i < NBINS) ? cnt2[i] : 0;
  #pragma unroll
  for (int s = 1; s < 64; s <<= 1) {
    int y = __shfl_up(x, s, 64);
    if (lane >= s) x += y;
  }
  if (lane == 63) wsum[wid] = x;
  __syncthreads();
  if (wid == 0) {
    int w = (lane < 16) ? wsum[lane] : 0;
    #pragma unroll
    for (int s = 1; s < 16; s <<= 1) {
      int y = __shfl_up(w, s, 64);
      if (lane >= s) w += y;
    }
    if (lane < 16) wsum[lane] = w;
  }
  __syncthreads();
  int wb = (wid > 0) ? wsum[wid - 1] : 0;
  tmp[i] = wb + x;
  if (t == 1023) bsum[b] = wsum[15];
}

// B) one wave scans the SCAN_BLOCKS block sums -> exclusive prefixes
__global__ __launch_bounds__(64) void scanB(const int* __restrict__ bsum,
                                            int* __restrict__ bpre) {
  int lane = threadIdx.x;
  int carry = 0;
  for (int base = 0; base < SCAN_BLOCKS; base += 64) {
    int idx = base + lane;
    int v = (idx < SCAN_BLOCKS) ? bsum[idx] : 0;
    int x = v;
    #pragma unroll
    for (int s = 1; s < 64; s <<= 1) {
      int y = __shfl_up(x, s, 64);
      if (lane >= s) x += y;
    }
    if (idx < SCAN_BLOCKS) bpre[idx] = carry + x - v;
    carry += __shfl(x, 63, 64);
  }
}

// C) offs2[i+1] = tmp[i] + bpre[block]
__global__ __launch_bounds__(1024) void scanC(const int* __restrict__ tmp,
                                              const int* __restrict__ bpre,
                                              int* __restrict__ offs2) {
  int b = blockIdx.x, t = threadIdx.x;
  int i = b * 1024 + t;
  if (i < NBINS) offs2[i + 1] = tmp[i] + bpre[b];
  if (i == 0) offs2[0] = 0;
}

__global__ void fill_kernel(const int* __restrict__ esrc, const int* __restrict__ edst,
                            const int* __restrict__ etype, const int* __restrict__ offs2,
                            const int* __restrict__ rank, int* __restrict__ payload) {
  int e = blockIdx.x * 256 + threadIdx.x;
  if (e >= N_EDGES) return;
  int key = edst[e] * 4 + etype[e];
  payload[offs2[key] + rank[e]] = esrc[e];
}

// ROUND-6 gather, verbatim (best measured). One wave per node; payload
// prefetched one dword/lane; src broadcast via __shfl; per-type segments
// with 4-wide unroll. r7/r8/r9 scalarization attempts all regressed
// (89-106 us, VALUBusy 59-90%). Do not retry.
__global__ __launch_bounds__(256) void gather_kernel(const int* __restrict__ offs2,
    const int* __restrict__ payload, const ushort_t* __restrict__ hb,
    ushort_t* __restrict__ S, float* __restrict__ cntf) {
  int n = blockIdx.x * 4 + (threadIdx.x >> 6);
  int lane = threadIdx.x & 63;
  if (n >= N_NODES) return;
  int bb[5];
  #pragma unroll
  for (int k = 0; k < 5; ++k) bb[k] = offs2[n * 4 + k];
  float a[4][2] = {{0.f, 0.f}, {0.f, 0.f}, {0.f, 0.f}, {0.f, 0.f}};
  const ushort_t* hrow = hb + 128 + lane * 2;
  for (int base = bb[0]; base < bb[4]; base += 64) {
    int lim = min(bb[4], base + 64);
    int cnt = lim - base;
    int pe = (lane < cnt) ? payload[base + lane] : 0;
    #pragma unroll
    for (int t = 0; t < 4; ++t) {
      int lo = max(bb[t], base), hi = min(bb[t + 1], lim);
      int i = lo;
      for (; i + 4 <= hi; i += 4) {
        int s0 = __shfl(pe, i - base, 64);
        int s1 = __shfl(pe, i + 1 - base, 64);
        int s2 = __shfl(pe, i + 2 - base, 64);
        int s3 = __shfl(pe, i + 3 - base, 64);
        unsigned int u0 = *(const unsigned int*)(hrow + (size_t)s0 * 256);
        unsigned int u1 = *(const unsigned int*)(hrow + (size_t)s1 * 256);
        unsigned int u2 = *(const unsigned int*)(hrow + (size_t)s2 * 256);
        unsigned int u3 = *(const unsigned int*)(hrow + (size_t)s3 * 256);
        a[t][0] += b2f(u0 & 0xffff) + b2f(u1 & 0xffff) + b2f(u2 & 0xffff) + b2f(u3 & 0xffff);
        a[t][1] += b2f(u0 >> 16) + b2f(u1 >> 16) + b2f(u2 >> 16) + b2f(u3 >> 16);
      }
      for (; i < hi; ++i) {
        int s0 = __shfl(pe, i - base, 64);
        unsigned int u0 = *(const unsigned int*)(hrow + (size_t)s0 * 256);
        a[t][0] += b2f(u0 & 0xffff);
        a[t][1] += b2f(u0 >> 16);
      }
    }
  }
  #pragma unroll
  for (int t = 0; t < 4; ++t) {
    unsigned int packed = (unsigned int)f2b(a[t][0]) | ((unsigned int)f2b(a[t][1]) << 16);
    *(unsigned int*)(S + (size_t)n * 512 + t * 128 + lane * 2) = packed;
    if (lane == 0) cntf[n * 4 + t] = (float)(bb[t + 1] - bb[t]);
  }
}

// ---- bf16 MFMA GEMM, 64(M)x128(N) tile, 4 waves (each 32x64), 16x16x32 ----
// K-loop staging via __builtin_amdgcn_global_load_lds width=16 (the m97
// pattern): no VGPR round-trip, no ds_writes, no staging addr VALU. Requires
// UNPADDED 64B LDS rows (lds dest = wave-uniform base + lane*16); round-12
// counters showed MODE-1 k-loop was staging-bound (VALUBusy 50%, MfmaUtil 11%,
// LDS 9 instr/iter vs 8 MFMA). Write path was already near-ideal (37.5 MB
// vs 38.4 ideal) -- r11 "write amplification" diagnosis was wrong.
// MODE 2: a-GEMM (K=512, N=128): val = acc + sum_t cnt[m][t]*b_msg[t][n]; bf16 -> ah a-part.
// MODE 1: GRU epilogue (permuted gate cols); h fp32 in place; bf16 h -> ah_next h-part.
template <int MODE>
__global__ __launch_bounds__(256) void mfma_gemm(
    const ushort_t* __restrict__ A, int lda, int K,
    const ushort_t* __restrict__ Bt,
    const float* __restrict__ bias, const float* __restrict__ b_msg,
    const float* __restrict__ cntf,
    ushort_t* __restrict__ ah_out, float* __restrict__ h) {
  __shared__ __align__(16) unsigned char smem[15360];
  ushort_t* As = (ushort_t*)smem;            // [64][32] unpadded (64B rows)
  ushort_t* Bs = (ushort_t*)(smem + 4096);   // [128][32] unpadded
  const int m0 = blockIdx.x * 64, n0 = blockIdx.y * 128;
  int tid = threadIdx.x;
  int wave = tid >> 6, lane = tid & 63;
  int wm = (wave & 1) * 32, wn = (wave >> 1) * 64;
  int quad = lane >> 4, l16 = lane & 15;

  // Async staging layout: wave w stages A rows [w*16, w*16+16) (1 KB chunk)
  // and B rows [w*32, w*32+32) (two 1 KB chunks). Lane i covers
  // row = base + (i>>2), 16B piece (i&3) -> LDS offset = wave_base + i*16.
  int sr = lane >> 2, sc = lane & 3;
  const ushort_t* gA  = A  + (size_t)(m0 + wave * 16 + sr) * lda + sc * 8;
  const ushort_t* gB0 = Bt + (size_t)(n0 + wave * 32 + sr) * K   + sc * 8;
  const ushort_t* gB1 = gB0 + (size_t)16 * K;
  ushort_t* lA  = As + wave * 512;           // wave-uniform LDS bases
  ushort_t* lB0 = Bs + wave * 1024;
  ushort_t* lB1 = Bs + wave * 1024 + 512;

  f32x4 acc[2][4];
  #pragma unroll
  for (int i = 0; i < 2; ++i)
    #pragma unroll
    for (int j = 0; j < 4; ++j) acc[i][j] = (f32x4){0.f, 0.f, 0.f, 0.f};

  for (int k0 = 0; k0 < K; k0 += 32) {
    gld16(gA + k0, lA);
    gld16(gB0 + k0, lB0);
    gld16(gB1 + k0, lB1);
    __syncthreads();   // drains vmcnt (async LDS writes land) + barrier
    bf16x8 af[2], bfr[4];
    #pragma unroll
    for (int i = 0; i < 2; ++i) af[i] = *(const bf16x8*)&As[(wm + i * 16 + l16) * 32 + quad * 8];
    #pragma unroll
    for (int j = 0; j < 4; ++j) bfr[j] = *(const bf16x8*)&Bs[(wn + j * 16 + l16) * 32 + quad * 8];
    #pragma unroll
    for (int i = 0; i < 2; ++i)
      #pragma unroll
      for (int j = 0; j < 4; ++j)
        acc[i][j] = __builtin_amdgcn_mfma_f32_16x16x32_bf16(af[i], bfr[j], acc[i][j], 0, 0, 0);
    __syncthreads();
  }
  // k-loop ends with a barrier: LDS is free for epilogue staging.

  if (MODE == 2) {
    // n0 == 0 (N=128). Two 32-row passes through LDS; 256B/row final stores.
    ushort_t* Ep = (ushort_t*)smem;
    float bm[4][4];  // [j][t]
    #pragma unroll
    for (int j = 0; j < 4; ++j)
      #pragma unroll
      for (int t = 0; t < 4; ++t)
        bm[j][t] = b_msg[t * 128 + wn + j * 16 + l16];
    #pragma unroll
    for (int p = 0; p < 2; ++p) {
      if (p) __syncthreads();
      #pragma unroll
      for (int reg = 0; reg < 4; ++reg) {
        int slot = (wm >> 5) * 16 + quad * 4 + reg;
        int m = m0 + wm + p * 16 + quad * 4 + reg;
        float4 c = *(const float4*)(cntf + (size_t)m * 4);
        #pragma unroll
        for (int j = 0; j < 4; ++j) {
          float val = acc[p][j][reg] + c.x * bm[j][0] + c.y * bm[j][1]
                                     + c.z * bm[j][2] + c.w * bm[j][3];
          Ep[slot * 136 + wn + j * 16 + l16] = f2b(val);
        }
      }
      __syncthreads();
      #pragma unroll
      for (int c2 = 0; c2 < 2; ++c2) {
        int chunk = tid + 256 * c2;            // 512 x 16B chunks = 32 rows x 256B
        int slot = chunk >> 4, sub = chunk & 15;
        int m = m0 + (slot & 15) + (slot >> 4) * 32 + p * 16;
        *(uint4*)(ah_out + (size_t)m * 256 + sub * 8) =
            *(const uint4*)&Ep[slot * 136 + sub * 8];
      }
    }
  } else {
    // Block covers dims [db, db+32) x 64 rows. Stage h fp32 + ah bf16 in LDS,
    // then full-line stores.
    float* Hp = (float*)smem;                       // 64 x 36 f32 = 9216B
    ushort_t* Ap = (ushort_t*)(smem + 9216);        // 64 x 40 us = 5120B
    int db = (n0 >> 6) * 16;
    int dim_loc = (wn >> 6) * 16 + l16;
    float br = bias[n0 + wn + l16];
    float bz = bias[n0 + wn + 16 + l16];
    float bi = bias[n0 + wn + 32 + l16];
    float bh = bias[n0 + wn + 48 + l16];
    #pragma unroll
    for (int i = 0; i < 2; ++i)
      #pragma unroll
      for (int reg = 0; reg < 4; ++reg) {
        int r_loc = wm + i * 16 + quad * 4 + reg;
        int m = m0 + r_loc;
        float pr  = acc[i][0][reg] + br;
        float pz  = acc[i][1][reg] + bz;
        float in_ = acc[i][2][reg] + bi;
        float hn  = acc[i][3][reg] + bh;
        float r = 1.0f / (1.0f + expf(-pr));
        float z = 1.0f / (1.0f + expf(-pz));
        float nn = tanhf(in_ + r * hn);
        size_t hi = (size_t)m * 128 + db + dim_loc;
        float hv = (1.0f - z) * nn + z * h[hi];
        Hp[r_loc * 36 + dim_loc] = hv;
        Ap[r_loc * 40 + dim_loc] = f2b(hv);
      }
    __syncthreads();
    #pragma unroll
    for (int c2 = 0; c2 < 2; ++c2) {
      int chunk = tid + 256 * c2;              // 512 x 16B = 64 rows x 128B (h)
      int row = chunk >> 3, sub = chunk & 7;
      *(uint4*)(h + (size_t)(m0 + row) * 128 + db + sub * 4) =
          *(const uint4*)&Hp[row * 36 + sub * 4];
    }
    {
      int row = tid >> 2, sub = tid & 3;       // 256 x 16B = 64 rows x 64B (ah)
      *(uint4*)(ah_out + (size_t)(m0 + row) * 256 + 128 + db + sub * 8) =
          *(const uint4*)&Ap[row * 40 + sub * 8];
    }
  }
}

// partial pooling: grid (graph, chunk); 8-way atomic contention max.
__global__ __launch_bounds__(128) void pool_kernel(const float* __restrict__ h,
    const int* __restrict__ gids, float* __restrict__ pooled, float* __restrict__ gcnt) {
  __shared__ int lo_s, hi_s;
  int g = blockIdx.x, c = blockIdx.y, d = threadIdx.x;
  if (d == 0) {
    int lo = 0, hi = N_NODES;
    while (lo < hi) { int mid = (lo + hi) >> 1; if (gids[mid] < g) lo = mid + 1; else hi = mid; }
    lo_s = lo;
    int lo2 = lo, hi2 = N_NODES;
    while (lo2 < hi2) { int mid = (lo2 + hi2) >> 1; if (gids[mid] < g + 1) lo2 = mid + 1; else hi2 = mid; }
    hi_s = lo2;
  }
  __syncthreads();
  int lo = lo_s, hi = hi_s;
  int len = hi - lo;
  int b = lo + (int)(((long long)len * c) >> 3);
  int e = lo + (int)(((long long)len * (c + 1)) >> 3);
  float s = 0.f;
  for (int n = b; n < e; ++n) s += h[(size_t)n * 128 + d];
  if (e > b) atomicAdd(&pooled[g * 128 + d], s);
  if (c == 0 && d == 0) gcnt[g] = (float)len;
}

__global__ __launch_bounds__(256) void classifier_kernel(
    const float* __restrict__ pooled, const float* __restrict__ gcnt,
    const float* __restrict__ W1, const float* __restrict__ b1,
    const float* __restrict__ W2, const float* __restrict__ b2,
    float* __restrict__ out) {
  __shared__ float p[D];
  __shared__ float hid[256];
  __shared__ float wsum[4];
  int g = blockIdx.x;
  int t = threadIdx.x;
  float cnt = fmaxf(gcnt[g], 1.0f);
  if (t < D) p[t] = pooled[g * D + t] / cnt;
  __syncthreads();
  float acc = b1[t];
  const float* w = W1 + (size_t)t * D;
  for (int k = 0; k < D; ++k) acc += p[k] * w[k];
  hid[t] = fmaxf(acc, 0.0f);
  __syncthreads();
  float v = hid[t] * W2[t];
  for (int off = 32; off > 0; off >>= 1) v += __shfl_down(v, off, 64);
  if ((t & 63) == 0) wsum[t >> 6] = v;
  __syncthreads();
  if (t == 0) {
    float s = wsum[0] + wsum[1] + wsum[2] + wsum[3] + b2[0];
    out[g] = 1.0f / (1.0f + expf(-s));
  }
}

extern "C" void kernel_launch(void* const* d_in, const int* in_sizes, int n_in,
                              void* d_out, int out_size, void* d_ws, size_t ws_size,
                              hipStream_t stream) {
  const float* features = (const float*)d_in[0];
  const int* esrc  = (const int*)d_in[1];
  const int* edst  = (const int*)d_in[2];
  const int* etype = (const int*)d_in[3];
  const int* gids  = (const int*)d_in[4];
  const float* W_msg = (const float*)d_in[5];
  const float* b_msg = (const float*)d_in[6];
  const float* W_ih  = (const float*)d_in[7];
  const float* W_hh  = (const float*)d_in[8];
  const float* b_ih  = (const float*)d_in[9];
  const float* b_hh  = (const float*)d_in[10];
  const float* W1 = (const float*)d_in[11];
  const float* b1 = (const float*)d_in[12];
  const float* W2 = (const float*)d_in[13];
  const float* b2 = (const float*)d_in[14];
  float* out = (float*)d_out;

  char* ws = (char*)d_ws;
  size_t off_b = 0;
  auto alloc = [&](size_t bytes) -> void* {
    void* p = ws + off_b;
    off_b += (bytes + 255) & ~(size_t)255;
    return p;
  };
  float*    h      = (float*)alloc((size_t)M_PAD * 128 * 4);      // 25.6 MB fp32 master
  ushort_t* ahA    = (ushort_t*)alloc((size_t)M_PAD * 256 * 2);   // [a|h] bf16
  ushort_t* ahB    = (ushort_t*)alloc((size_t)M_PAD * 256 * 2);   // ping-pong partner
  ushort_t* S      = (ushort_t*)alloc((size_t)M_PAD * 512 * 2);   // 51.2 MB bf16
  float*    cntf   = (float*)alloc((size_t)M_PAD * 4 * 4);        // per-node type counts
  ushort_t* BtS    = (ushort_t*)alloc(128 * 512 * 2);
  ushort_t* WgT    = (ushort_t*)alloc(512 * 256 * 2);
  float*    gbias  = (float*)alloc(512 * 4);
  int*      cnt2   = (int*)alloc((size_t)NBINS * 4);
  int*      offs2  = (int*)alloc((size_t)(NBINS + 1) * 4);
  int*      rank   = (int*)alloc((size_t)N_EDGES * 4);
  int*      tmp    = (int*)alloc((size_t)SCAN_BLOCKS * 1024 * 4);
  int*      bsum   = (int*)alloc(SCAN_BLOCKS * 4);
  int*      bpre   = (int*)alloc(SCAN_BLOCKS * 4);
  int*      payload= (int*)alloc((size_t)N_EDGES * 4);
  float*    pooled = (float*)alloc(N_GRAPHS * 128 * 4);
  float*    gcnt   = (float*)alloc(N_GRAPHS * 4);

  // ---- prologue ----
  pad_cast_kernel<<<(N_NODES * 128 + 255) / 256, 256, 0, stream>>>(features, h, ahA);
  prep_bts<<<(128 * 512 + 255) / 256, 256, 0, stream>>>(W_msg, BtS);
  prep_wg<<<(512 * 256 + 255) / 256, 256, 0, stream>>>(W_ih, W_hh, b_ih, b_hh, WgT, gbias);
  hipMemsetAsync(cnt2, 0, (size_t)NBINS * 4, stream);
  hist_kernel<<<(N_EDGES + 255) / 256, 256, 0, stream>>>(edst, etype, cnt2, rank);
  scanA<<<SCAN_BLOCKS, 1024, 0, stream>>>(cnt2, tmp, bsum);
  scanB<<<1, 64, 0, stream>>>(bsum, bpre);
  scanC<<<SCAN_BLOCKS, 1024, 0, stream>>>(tmp, bpre, offs2);
  fill_kernel<<<(N_EDGES + 255) / 256, 256, 0, stream>>>(esrc, edst, etype, offs2, rank, payload);

  ushort_t* cur = ahA;
  ushort_t* nxt = ahB;
  for (int step = 0; step < N_STEPS; ++step) {
    // S[n][t][:] = sum of h_src (bf16) over type-t in-edges
    gather_kernel<<<(N_NODES + 3) / 4, 256, 0, stream>>>(offs2, payload, cur, S, cntf);
    // a-part of cur = bf16(S @ [W_0;..;W_3] + cnt-weighted b_msg)
    mfma_gemm<2><<<dim3(M_PAD / 64, 1), 256, 0, stream>>>(
        S, 512, 512, BtS, nullptr, b_msg, cntf, cur, nullptr);
    // fused GRU GEMM + gate epilogue: fp32 h in place, bf16 h into nxt
    mfma_gemm<1><<<dim3(M_PAD / 64, 4), 256, 0, stream>>>(
        cur, 256, 256, WgT, gbias, nullptr, nullptr, nxt, h);
    ushort_t* t2 = cur; cur = nxt; nxt = t2;
  }

  hipMemsetAsync(pooled, 0, (size_t)N_GRAPHS * 128 * 4, stream);
  pool_kernel<<<dim3(N_GRAPHS, 8), 128, 0, stream>>>(h, gids, pooled, gcnt);
  classifier_kernel<<<N_GRAPHS, 256, 0, stream>>>(pooled, gcnt, W1, b1, W2, b2, out);
}

// Round 14
// 957.808 us; speedup vs baseline: 1.0440x; 1.0327x over previous
//
#include <hip/hip_runtime.h>
#include <hip/hip_bf16.h>
#include <math.h>

#define N_NODES 50000
#define M_PAD   50048   // 782 * 64
#define N_EDGES 800000
#define N_GRAPHS 100
#define IN_DIM 100
#define D 128
#define N_STEPS 8
#define NBINS (N_NODES * 4)      // (dst, type) bins
#define SCAN_BLOCKS 196          // 196*1024 = 200704 >= NBINS

typedef unsigned short ushort_t;
typedef __bf16 bf16x8 __attribute__((ext_vector_type(8)));
typedef float f32x4 __attribute__((ext_vector_type(4)));

__device__ inline ushort_t f2b(float f) {
  __hip_bfloat16 b = __float2bfloat16(f);
  return *reinterpret_cast<ushort_t*>(&b);
}
__device__ inline float b2f(unsigned int u16) {
  unsigned int x = u16 << 16;
  return __builtin_bit_cast(float, x);
}

// async global->LDS, 16B per lane; lds dest = wave-uniform base + lane*16.
__device__ __attribute__((always_inline)) inline void gld16(const ushort_t* g, ushort_t* l) {
  __builtin_amdgcn_global_load_lds(
      (const __attribute__((address_space(1))) void*)g,
      (__attribute__((address_space(3))) void*)l, 16, 0, 0);
}

// h state is bf16-only (fp32 master eliminated round 14: it cost 51.2 MB/step
// of MODE-1 traffic and the state already entered every GEMM as bf16).
__global__ void pad_cast_kernel(const float* __restrict__ feat, ushort_t* __restrict__ ah) {
  int idx = blockIdx.x * blockDim.x + threadIdx.x;
  if (idx >= N_NODES * D) return;
  int n = idx >> 7, d = idx & 127;
  float v = (d < IN_DIM) ? feat[n * IN_DIM + d] : 0.0f;
  ah[(size_t)n * 256 + 128 + d] = f2b(v);
}

// BtS[f][t*128+k] = bf16(W_msg[t][k][f])   (n-major, k-contiguous, K=512)
__global__ void prep_bts(const float* __restrict__ W_msg, ushort_t* __restrict__ BtS) {
  int idx = blockIdx.x * blockDim.x + threadIdx.x;
  if (idx >= 128 * 512) return;
  int f = idx >> 9, kp = idx & 511;
  int t = kp >> 7, k = kp & 127;
  BtS[(size_t)f * 512 + kp] = f2b(W_msg[((size_t)t * 128 + k) * 128 + f]);
}

// Permuted fused GRU weight, n-major k-contiguous bf16.
// col' = g*64 + gate*16 + r ; dim d = g*16 + r ; K: k<128 = a (W_ih), k>=128 = h (W_hh)
__global__ void prep_wg(const float* __restrict__ W_ih, const float* __restrict__ W_hh,
                        const float* __restrict__ b_ih, const float* __restrict__ b_hh,
                        ushort_t* __restrict__ WgT, float* __restrict__ gbias) {
  int idx = blockIdx.x * blockDim.x + threadIdx.x;
  if (idx >= 512 * 256) return;
  int colp = idx >> 8, k = idx & 255;
  int g = colp >> 6, gate = (colp >> 4) & 3, r = colp & 15;
  int d = g * 16 + r;
  float v;
  if (gate == 3)      v = (k < 128) ? 0.f : W_hh[(size_t)(256 + d) * 128 + (k - 128)];
  else if (gate == 2) v = (k < 128) ? W_ih[(size_t)(256 + d) * 128 + k] : 0.f;
  else {
    int j0 = (gate == 0) ? d : 128 + d;
    v = (k < 128) ? W_ih[(size_t)j0 * 128 + k] : W_hh[(size_t)j0 * 128 + (k - 128)];
  }
  WgT[(size_t)colp * 256 + k] = f2b(v);
  if (k == 0) {
    float bb = (gate == 0) ? b_ih[d] + b_hh[d]
             : (gate == 1) ? b_ih[128 + d] + b_hh[128 + d]
             : (gate == 2) ? b_ih[256 + d] : b_hh[256 + d];
    gbias[colp] = bb;
  }
}

// ---- type-segmented CSR build over NBINS = dst*4+type ----
__global__ void hist_kernel(const int* __restrict__ edst, const int* __restrict__ etype,
                            int* __restrict__ cnt2, int* __restrict__ rank) {
  int e = blockIdx.x * 256 + threadIdx.x;
  if (e >= N_EDGES) return;
  rank[e] = atomicAdd(&cnt2[edst[e] * 4 + etype[e]], 1);
}

// 3-phase scan: A) per-block inclusive scan + block sums
__global__ __launch_bounds__(1024) void scanA(const int* __restrict__ cnt2,
                                              int* __restrict__ tmp, int* __restrict__ bsum) {
  __shared__ int wsum[16];
  int b = blockIdx.x, t = threadIdx.x;
  int i = b * 1024 + t;
  int lane = t & 63, wid = t >> 6;
  int x = (i < NBINS) ? cnt2[i] : 0;
  #pragma unroll
  for (int s = 1; s < 64; s <<= 1) {
    int y = __shfl_up(x, s, 64);
    if (lane >= s) x += y;
  }
  if (lane == 63) wsum[wid] = x;
  __syncthreads();
  if (wid == 0) {
    int w = (lane < 16) ? wsum[lane] : 0;
    #pragma unroll
    for (int s = 1; s < 16; s <<= 1) {
      int y = __shfl_up(w, s, 64);
      if (lane >= s) w += y;
    }
    if (lane < 16) wsum[lane] = w;
  }
  __syncthreads();
  int wb = (wid > 0) ? wsum[wid - 1] : 0;
  tmp[i] = wb + x;
  if (t == 1023) bsum[b] = wsum[15];
}

// B) one wave scans the SCAN_BLOCKS block sums -> exclusive prefixes
__global__ __launch_bounds__(64) void scanB(const int* __restrict__ bsum,
                                            int* __restrict__ bpre) {
  int lane = threadIdx.x;
  int carry = 0;
  for (int base = 0; base < SCAN_BLOCKS; base += 64) {
    int idx = base + lane;
    int v = (idx < SCAN_BLOCKS) ? bsum[idx] : 0;
    int x = v;
    #pragma unroll
    for (int s = 1; s < 64; s <<= 1) {
      int y = __shfl_up(x, s, 64);
      if (lane >= s) x += y;
    }
    if (idx < SCAN_BLOCKS) bpre[idx] = carry + x - v;
    carry += __shfl(x, 63, 64);
  }
}

// C) offs2[i+1] = tmp[i] + bpre[block]
__global__ __launch_bounds__(1024) void scanC(const int* __restrict__ tmp,
                                              const int* __restrict__ bpre,
                                              int* __restrict__ offs2) {
  int b = blockIdx.x, t = threadIdx.x;
  int i = b * 1024 + t;
  if (i < NBINS) offs2[i + 1] = tmp[i] + bpre[b];
  if (i == 0) offs2[0] = 0;
}

__global__ void fill_kernel(const int* __restrict__ esrc, const int* __restrict__ edst,
                            const int* __restrict__ etype, const int* __restrict__ offs2,
                            const int* __restrict__ rank, int* __restrict__ payload) {
  int e = blockIdx.x * 256 + threadIdx.x;
  if (e >= N_EDGES) return;
  int key = edst[e] * 4 + etype[e];
  payload[offs2[key] + rank[e]] = esrc[e];
}

// ROUND-6 gather, verbatim (best measured). One wave per node; payload
// prefetched one dword/lane; src broadcast via __shfl; per-type segments
// with 4-wide unroll. r7/r8/r9 scalarization attempts all regressed
// (89-106 us, VALUBusy 59-90%). Do not retry.
__global__ __launch_bounds__(256) void gather_kernel(const int* __restrict__ offs2,
    const int* __restrict__ payload, const ushort_t* __restrict__ hb,
    ushort_t* __restrict__ S, float* __restrict__ cntf) {
  int n = blockIdx.x * 4 + (threadIdx.x >> 6);
  int lane = threadIdx.x & 63;
  if (n >= N_NODES) return;
  int bb[5];
  #pragma unroll
  for (int k = 0; k < 5; ++k) bb[k] = offs2[n * 4 + k];
  float a[4][2] = {{0.f, 0.f}, {0.f, 0.f}, {0.f, 0.f}, {0.f, 0.f}};
  const ushort_t* hrow = hb + 128 + lane * 2;
  for (int base = bb[0]; base < bb[4]; base += 64) {
    int lim = min(bb[4], base + 64);
    int cnt = lim - base;
    int pe = (lane < cnt) ? payload[base + lane] : 0;
    #pragma unroll
    for (int t = 0; t < 4; ++t) {
      int lo = max(bb[t], base), hi = min(bb[t + 1], lim);
      int i = lo;
      for (; i + 4 <= hi; i += 4) {
        int s0 = __shfl(pe, i - base, 64);
        int s1 = __shfl(pe, i + 1 - base, 64);
        int s2 = __shfl(pe, i + 2 - base, 64);
        int s3 = __shfl(pe, i + 3 - base, 64);
        unsigned int u0 = *(const unsigned int*)(hrow + (size_t)s0 * 256);
        unsigned int u1 = *(const unsigned int*)(hrow + (size_t)s1 * 256);
        unsigned int u2 = *(const unsigned int*)(hrow + (size_t)s2 * 256);
        unsigned int u3 = *(const unsigned int*)(hrow + (size_t)s3 * 256);
        a[t][0] += b2f(u0 & 0xffff) + b2f(u1 & 0xffff) + b2f(u2 & 0xffff) + b2f(u3 & 0xffff);
        a[t][1] += b2f(u0 >> 16) + b2f(u1 >> 16) + b2f(u2 >> 16) + b2f(u3 >> 16);
      }
      for (; i < hi; ++i) {
        int s0 = __shfl(pe, i - base, 64);
        unsigned int u0 = *(const unsigned int*)(hrow + (size_t)s0 * 256);
        a[t][0] += b2f(u0 & 0xffff);
        a[t][1] += b2f(u0 >> 16);
      }
    }
  }
  #pragma unroll
  for (int t = 0; t < 4; ++t) {
    unsigned int packed = (unsigned int)f2b(a[t][0]) | ((unsigned int)f2b(a[t][1]) << 16);
    *(unsigned int*)(S + (size_t)n * 512 + t * 128 + lane * 2) = packed;
    if (lane == 0) cntf[n * 4 + t] = (float)(bb[t + 1] - bb[t]);
  }
}

// ---- bf16 MFMA GEMM, 64(M)x128(N) tile, 4 waves (each 32x64), 16x16x32 ----
// K-loop staging via global_load_lds width=16 (unpadded 64B LDS rows).
// MODE 2: a-GEMM (K=512, N=128): val = acc + sum_t cnt[m][t]*b_msg[t][n]; bf16 -> ah a-part.
// MODE 1: GRU epilogue; h_old read as bf16 from the A input itself (L2-hot),
//         only bf16 h written to ah_next -- no fp32 state (round-14 change:
//         fp32 master cost 51.2 MB/step and bought no measurable accuracy).
template <int MODE>
__global__ __launch_bounds__(256) void mfma_gemm(
    const ushort_t* __restrict__ A, int lda, int K,
    const ushort_t* __restrict__ Bt,
    const float* __restrict__ bias, const float* __restrict__ b_msg,
    const float* __restrict__ cntf,
    ushort_t* __restrict__ ah_out) {
  __shared__ __align__(16) unsigned char smem[15360];
  ushort_t* As = (ushort_t*)smem;            // [64][32] unpadded (64B rows)
  ushort_t* Bs = (ushort_t*)(smem + 4096);   // [128][32] unpadded
  const int m0 = blockIdx.x * 64, n0 = blockIdx.y * 128;
  int tid = threadIdx.x;
  int wave = tid >> 6, lane = tid & 63;
  int wm = (wave & 1) * 32, wn = (wave >> 1) * 64;
  int quad = lane >> 4, l16 = lane & 15;

  int sr = lane >> 2, sc = lane & 3;
  const ushort_t* gA  = A  + (size_t)(m0 + wave * 16 + sr) * lda + sc * 8;
  const ushort_t* gB0 = Bt + (size_t)(n0 + wave * 32 + sr) * K   + sc * 8;
  const ushort_t* gB1 = gB0 + (size_t)16 * K;
  ushort_t* lA  = As + wave * 512;
  ushort_t* lB0 = Bs + wave * 1024;
  ushort_t* lB1 = Bs + wave * 1024 + 512;

  f32x4 acc[2][4];
  #pragma unroll
  for (int i = 0; i < 2; ++i)
    #pragma unroll
    for (int j = 0; j < 4; ++j) acc[i][j] = (f32x4){0.f, 0.f, 0.f, 0.f};

  for (int k0 = 0; k0 < K; k0 += 32) {
    gld16(gA + k0, lA);
    gld16(gB0 + k0, lB0);
    gld16(gB1 + k0, lB1);
    __syncthreads();   // drains vmcnt (async LDS writes land) + barrier
    bf16x8 af[2], bfr[4];
    #pragma unroll
    for (int i = 0; i < 2; ++i) af[i] = *(const bf16x8*)&As[(wm + i * 16 + l16) * 32 + quad * 8];
    #pragma unroll
    for (int j = 0; j < 4; ++j) bfr[j] = *(const bf16x8*)&Bs[(wn + j * 16 + l16) * 32 + quad * 8];
    #pragma unroll
    for (int i = 0; i < 2; ++i)
      #pragma unroll
      for (int j = 0; j < 4; ++j)
        acc[i][j] = __builtin_amdgcn_mfma_f32_16x16x32_bf16(af[i], bfr[j], acc[i][j], 0, 0, 0);
    __syncthreads();
  }
  // k-loop ends with a barrier: LDS is free for epilogue staging.

  if (MODE == 2) {
    // n0 == 0 (N=128). Two 32-row passes through LDS; 256B/row final stores.
    ushort_t* Ep = (ushort_t*)smem;
    float bm[4][4];  // [j][t]
    #pragma unroll
    for (int j = 0; j < 4; ++j)
      #pragma unroll
      for (int t = 0; t < 4; ++t)
        bm[j][t] = b_msg[t * 128 + wn + j * 16 + l16];
    #pragma unroll
    for (int p = 0; p < 2; ++p) {
      if (p) __syncthreads();
      #pragma unroll
      for (int reg = 0; reg < 4; ++reg) {
        int slot = (wm >> 5) * 16 + quad * 4 + reg;
        int m = m0 + wm + p * 16 + quad * 4 + reg;
        float4 c = *(const float4*)(cntf + (size_t)m * 4);
        #pragma unroll
        for (int j = 0; j < 4; ++j) {
          float val = acc[p][j][reg] + c.x * bm[j][0] + c.y * bm[j][1]
                                     + c.z * bm[j][2] + c.w * bm[j][3];
          Ep[slot * 136 + wn + j * 16 + l16] = f2b(val);
        }
      }
      __syncthreads();
      #pragma unroll
      for (int c2 = 0; c2 < 2; ++c2) {
        int chunk = tid + 256 * c2;            // 512 x 16B chunks = 32 rows x 256B
        int slot = chunk >> 4, sub = chunk & 15;
        int m = m0 + (slot & 15) + (slot >> 4) * 32 + p * 16;
        *(uint4*)(ah_out + (size_t)m * 256 + sub * 8) =
            *(const uint4*)&Ep[slot * 136 + sub * 8];
      }
    }
  } else {
    // Block covers dims [db, db+32) x 64 rows. h_old = bf16 from A (this
    // kernel's own input, L2-hot). Stage bf16 h in LDS; 64B-row stores.
    ushort_t* Ap = (ushort_t*)smem;                 // 64 x 40 us = 5120B
    int db = (n0 >> 6) * 16;
    int dim_loc = (wn >> 6) * 16 + l16;
    float br = bias[n0 + wn + l16];
    float bz = bias[n0 + wn + 16 + l16];
    float bi = bias[n0 + wn + 32 + l16];
    float bh = bias[n0 + wn + 48 + l16];
    #pragma unroll
    for (int i = 0; i < 2; ++i)
      #pragma unroll
      for (int reg = 0; reg < 4; ++reg) {
        int r_loc = wm + i * 16 + quad * 4 + reg;
        int m = m0 + r_loc;
        float pr  = acc[i][0][reg] + br;
        float pz  = acc[i][1][reg] + bz;
        float in_ = acc[i][2][reg] + bi;
        float hn  = acc[i][3][reg] + bh;
        float r = 1.0f / (1.0f + expf(-pr));
        float z = 1.0f / (1.0f + expf(-pz));
        float nn = tanhf(in_ + r * hn);
        float hold = b2f(A[(size_t)m * lda + 128 + db + dim_loc]);
        float hv = (1.0f - z) * nn + z * hold;
        Ap[r_loc * 40 + dim_loc] = f2b(hv);
      }
    __syncthreads();
    {
      int row = tid >> 2, sub = tid & 3;       // 256 x 16B = 64 rows x 64B (ah)
      *(uint4*)(ah_out + (size_t)(m0 + row) * 256 + 128 + db + sub * 8) =
          *(const uint4*)&Ap[row * 40 + sub * 8];
    }
  }
}

// partial pooling over bf16 h: grid (graph, chunk); 8-way atomic contention max.
__global__ __launch_bounds__(128) void pool_kernel(const ushort_t* __restrict__ ah,
    const int* __restrict__ gids, float* __restrict__ pooled, float* __restrict__ gcnt) {
  __shared__ int lo_s, hi_s;
  int g = blockIdx.x, c = blockIdx.y, d = threadIdx.x;
  if (d == 0) {
    int lo = 0, hi = N_NODES;
    while (lo < hi) { int mid = (lo + hi) >> 1; if (gids[mid] < g) lo = mid + 1; else hi = mid; }
    lo_s = lo;
    int lo2 = lo, hi2 = N_NODES;
    while (lo2 < hi2) { int mid = (lo2 + hi2) >> 1; if (gids[mid] < g + 1) lo2 = mid + 1; else hi2 = mid; }
    hi_s = lo2;
  }
  __syncthreads();
  int lo = lo_s, hi = hi_s;
  int len = hi - lo;
  int b = lo + (int)(((long long)len * c) >> 3);
  int e = lo + (int)(((long long)len * (c + 1)) >> 3);
  float s = 0.f;
  for (int n = b; n < e; ++n) s += b2f(ah[(size_t)n * 256 + 128 + d]);
  if (e > b) atomicAdd(&pooled[g * 128 + d], s);
  if (c == 0 && d == 0) gcnt[g] = (float)len;
}

__global__ __launch_bounds__(256) void classifier_kernel(
    const float* __restrict__ pooled, const float* __restrict__ gcnt,
    const float* __restrict__ W1, const float* __restrict__ b1,
    const float* __restrict__ W2, const float* __restrict__ b2,
    float* __restrict__ out) {
  __shared__ float p[D];
  __shared__ float hid[256];
  __shared__ float wsum[4];
  int g = blockIdx.x;
  int t = threadIdx.x;
  float cnt = fmaxf(gcnt[g], 1.0f);
  if (t < D) p[t] = pooled[g * D + t] / cnt;
  __syncthreads();
  float acc = b1[t];
  const float* w = W1 + (size_t)t * D;
  for (int k = 0; k < D; ++k) acc += p[k] * w[k];
  hid[t] = fmaxf(acc, 0.0f);
  __syncthreads();
  float v = hid[t] * W2[t];
  for (int off = 32; off > 0; off >>= 1) v += __shfl_down(v, off, 64);
  if ((t & 63) == 0) wsum[t >> 6] = v;
  __syncthreads();
  if (t == 0) {
    float s = wsum[0] + wsum[1] + wsum[2] + wsum[3] + b2[0];
    out[g] = 1.0f / (1.0f + expf(-s));
  }
}

extern "C" void kernel_launch(void* const* d_in, const int* in_sizes, int n_in,
                              void* d_out, int out_size, void* d_ws, size_t ws_size,
                              hipStream_t stream) {
  const float* features = (const float*)d_in[0];
  const int* esrc  = (const int*)d_in[1];
  const int* edst  = (const int*)d_in[2];
  const int* etype = (const int*)d_in[3];
  const int* gids  = (const int*)d_in[4];
  const float* W_msg = (const float*)d_in[5];
  const float* b_msg = (const float*)d_in[6];
  const float* W_ih  = (const float*)d_in[7];
  const float* W_hh  = (const float*)d_in[8];
  const float* b_ih  = (const float*)d_in[9];
  const float* b_hh  = (const float*)d_in[10];
  const float* W1 = (const float*)d_in[11];
  const float* b1 = (const float*)d_in[12];
  const float* W2 = (const float*)d_in[13];
  const float* b2 = (const float*)d_in[14];
  float* out = (float*)d_out;

  char* ws = (char*)d_ws;
  size_t off_b = 0;
  auto alloc = [&](size_t bytes) -> void* {
    void* p = ws + off_b;
    off_b += (bytes + 255) & ~(size_t)255;
    return p;
  };
  ushort_t* ahA    = (ushort_t*)alloc((size_t)M_PAD * 256 * 2);   // [a|h] bf16
  ushort_t* ahB    = (ushort_t*)alloc((size_t)M_PAD * 256 * 2);   // ping-pong partner
  ushort_t* S      = (ushort_t*)alloc((size_t)M_PAD * 512 * 2);   // 51.2 MB bf16
  float*    cntf   = (float*)alloc((size_t)M_PAD * 4 * 4);        // per-node type counts
  ushort_t* BtS    = (ushort_t*)alloc(128 * 512 * 2);
  ushort_t* WgT    = (ushort_t*)alloc(512 * 256 * 2);
  float*    gbias  = (float*)alloc(512 * 4);
  int*      cnt2   = (int*)alloc((size_t)NBINS * 4);
  int*      offs2  = (int*)alloc((size_t)(NBINS + 1) * 4);
  int*      rank   = (int*)alloc((size_t)N_EDGES * 4);
  int*      tmp    = (int*)alloc((size_t)SCAN_BLOCKS * 1024 * 4);
  int*      bsum   = (int*)alloc(SCAN_BLOCKS * 4);
  int*      bpre   = (int*)alloc(SCAN_BLOCKS * 4);
  int*      payload= (int*)alloc((size_t)N_EDGES * 4);
  float*    pooled = (float*)alloc(N_GRAPHS * 128 * 4);
  float*    gcnt   = (float*)alloc(N_GRAPHS * 4);

  // ---- prologue ----
  pad_cast_kernel<<<(N_NODES * 128 + 255) / 256, 256, 0, stream>>>(features, ahA);
  prep_bts<<<(128 * 512 + 255) / 256, 256, 0, stream>>>(W_msg, BtS);
  prep_wg<<<(512 * 256 + 255) / 256, 256, 0, stream>>>(W_ih, W_hh, b_ih, b_hh, WgT, gbias);
  hipMemsetAsync(cnt2, 0, (size_t)NBINS * 4, stream);
  hist_kernel<<<(N_EDGES + 255) / 256, 256, 0, stream>>>(edst, etype, cnt2, rank);
  scanA<<<SCAN_BLOCKS, 1024, 0, stream>>>(cnt2, tmp, bsum);
  scanB<<<1, 64, 0, stream>>>(bsum, bpre);
  scanC<<<SCAN_BLOCKS, 1024, 0, stream>>>(tmp, bpre, offs2);
  fill_kernel<<<(N_EDGES + 255) / 256, 256, 0, stream>>>(esrc, edst, etype, offs2, rank, payload);

  ushort_t* cur = ahA;
  ushort_t* nxt = ahB;
  for (int step = 0; step < N_STEPS; ++step) {
    // S[n][t][:] = sum of h_src (bf16) over type-t in-edges
    gather_kernel<<<(N_NODES + 3) / 4, 256, 0, stream>>>(offs2, payload, cur, S, cntf);
    // a-part of cur = bf16(S @ [W_0;..;W_3] + cnt-weighted b_msg)
    mfma_gemm<2><<<dim3(M_PAD / 64, 1), 256, 0, stream>>>(
        S, 512, 512, BtS, nullptr, b_msg, cntf, cur);
    // fused GRU GEMM + gate epilogue: bf16 h into nxt (h_old read from cur)
    mfma_gemm<1><<<dim3(M_PAD / 64, 4), 256, 0, stream>>>(
        cur, 256, 256, WgT, gbias, nullptr, nullptr, nxt);
    ushort_t* t2 = cur; cur = nxt; nxt = t2;
  }

  hipMemsetAsync(pooled, 0, (size_t)N_GRAPHS * 128 * 4, stream);
  pool_kernel<<<dim3(N_GRAPHS, 8), 128, 0, stream>>>(cur, gids, pooled, gcnt);
  classifier_kernel<<<N_GRAPHS, 256, 0, stream>>>(pooled, gcnt, W1, b1, W2, b2, out);
}